// Round 6
// baseline (374.710 us; speedup 1.0000x reference)
//
#include <hip/hip_runtime.h>
#include <cstdint>
#include <cstddef>

#define N_NODES 100000
#define N_EDGES 1600000
#define IN_CH   128
#define HID_CH  128
#define OUT_CH  64

#define NBLK ((N_NODES + 255) / 256)     // 391
#define FILL_CHUNK 2048
#define FILL_NCHUNK ((N_EDGES + FILL_CHUNK - 1) / FILL_CHUNK)  // 782
#define AGG_BLOCKS 2048

#define SH 8
#define SHRANGE 12500                     // dst / 12500 -> shard 0..7 (balanced)
#define BCAP 208896                       // per-shard pair capacity (~21 sigma slack)
#define P2_GRID 1024                      // pass-2 blocks: &7 = shard (XCD-aligned)

__device__ __forceinline__ unsigned short f2bf(float f) {
    unsigned int u = __float_as_uint(f);
    unsigned int r = (u + 0x7FFFu + ((u >> 16) & 1u)) >> 16;   // RNE
    return (unsigned short)r;
}
__device__ __forceinline__ float bfbits2f(unsigned int lo16) {
    return __uint_as_float(lo16 << 16);
}

// ---------------- CSR build: bucket pass ----------------
// Read ei once; dense sequential writes of (dst,src) pairs into 8 dst-range
// buckets. One global atomic per shard per block (6256 total).
__global__ __launch_bounds__(256) void k_bucket(const int* __restrict__ ei,
                                                int* __restrict__ gcur,
                                                int2* __restrict__ buckets) {
    __shared__ int scount[SH];
    __shared__ int sbase[SH];
    const int tid  = threadIdx.x;
    const int base = blockIdx.x * FILL_CHUNK;
    if (tid < SH) scount[tid] = 0;
    __syncthreads();
    int dv[8], sv[8], sh[8], rk[8];
    #pragma unroll
    for (int k = 0; k < 8; k++) {
        int e = base + k * 256 + tid;
        if (e < N_EDGES) {
            dv[k] = __builtin_nontemporal_load(ei + N_EDGES + e);
            sv[k] = __builtin_nontemporal_load(ei + e);
            sh[k] = dv[k] / SHRANGE;
            rk[k] = atomicAdd(&scount[sh[k]], 1);   // LDS atomic
        } else sh[k] = -1;
    }
    __syncthreads();
    if (tid < SH) sbase[tid] = atomicAdd(&gcur[tid], scount[tid]);
    __syncthreads();
    #pragma unroll
    for (int k = 0; k < 8; k++) {
        if (sh[k] >= 0) {
            int pos = sbase[sh[k]] + rk[k];
            if (pos < BCAP)
                buckets[(size_t)sh[k] * BCAP + pos] = make_int2(dv[k], sv[k]);
        }
    }
}

// Pass 2a: count. Shard s blocks read only bucket s (1.6MB) and hit a 50KB
// deg slice -> stays L2-resident on one XCD.
__global__ __launch_bounds__(256) void k_countB(const int2* __restrict__ buckets,
                                                const int* __restrict__ gcur,
                                                int* __restrict__ deg) {
    const int s = blockIdx.x & 7;
    const int j = blockIdx.x >> 3;
    const int n = gcur[s];
    const long long* bp = (const long long*)(buckets + (size_t)s * BCAP);
    for (int idx = j * 256 + threadIdx.x; idx < n; idx += (P2_GRID / 8) * 256) {
        long long v = __builtin_nontemporal_load(bp + idx);
        atomicAdd(&deg[(int)v], 1);
    }
}

// Pass 2b: fill. Same sharding; scatter srcs into an 800KB slice.
__global__ __launch_bounds__(256) void k_fillB(const int2* __restrict__ buckets,
                                               const int* __restrict__ gcur,
                                               int* __restrict__ cursor,
                                               int* __restrict__ srcs) {
    const int s = blockIdx.x & 7;
    const int j = blockIdx.x >> 3;
    const int n = gcur[s];
    const long long* bp = (const long long*)(buckets + (size_t)s * BCAP);
    for (int idx = j * 256 + threadIdx.x; idx < n; idx += (P2_GRID / 8) * 256) {
        long long v = __builtin_nontemporal_load(bp + idx);
        int d  = (int)v;
        int sv = (int)(v >> 32);
        int pos = atomicAdd(&cursor[d], 1);
        srcs[pos] = sv;
    }
}

// ---------------- scans ----------------
__global__ __launch_bounds__(256) void ks1(const int* __restrict__ deg,
                                           int* __restrict__ rowptr,
                                           int* __restrict__ bsum) {
    __shared__ int ws[4];
    const int t = threadIdx.x, lane = t & 63, wv = t >> 6;
    const int i = blockIdx.x * 256 + t;
    int v = (i < N_NODES) ? deg[i] : 0;
    int x = v;
    #pragma unroll
    for (int d = 1; d < 64; d <<= 1) {
        int y = __shfl_up(x, d, 64);
        if (lane >= d) x += y;
    }
    if (lane == 63) ws[wv] = x;
    __syncthreads();
    if (t == 0) {
        int c = 0;
        #pragma unroll
        for (int k = 0; k < 4; k++) { int tmp = ws[k]; ws[k] = c; c += tmp; }
        bsum[blockIdx.x] = c;
    }
    __syncthreads();
    if (i < N_NODES) rowptr[i] = ws[wv] + (x - v);
}

__global__ __launch_bounds__(512) void ks2(int* __restrict__ bsum,
                                           int* __restrict__ rowptr) {
    __shared__ int ws[8];
    const int t = threadIdx.x, lane = t & 63, wv = t >> 6;
    int v = (t < NBLK) ? bsum[t] : 0;
    int x = v;
    #pragma unroll
    for (int d = 1; d < 64; d <<= 1) {
        int y = __shfl_up(x, d, 64);
        if (lane >= d) x += y;
    }
    if (lane == 63) ws[wv] = x;
    __syncthreads();
    if (wv == 0) {
        int s = (lane < 8) ? ws[lane] : 0;
        #pragma unroll
        for (int d = 1; d < 8; d <<= 1) {
            int y = __shfl_up(s, d, 64);
            if (lane >= d) s += y;
        }
        if (lane < 8) ws[lane] = s;
    }
    __syncthreads();
    int waveoff = (wv == 0) ? 0 : ws[wv - 1];
    if (t < NBLK) bsum[t] = waveoff + (x - v);
    if (t == 0) rowptr[N_NODES] = ws[7];
}

__global__ void ks3(const int* __restrict__ deg, int* __restrict__ rowptr,
                    int* __restrict__ cursor, float* __restrict__ dinv,
                    const int* __restrict__ bsum) {
    int i = blockIdx.x * 256 + threadIdx.x;
    if (i < N_NODES) {
        int v = rowptr[i] + bsum[blockIdx.x];
        rowptr[i] = v;
        cursor[i] = v;
        dinv[i]   = rsqrtf((float)(deg[i] + 1));
    }
}

// ---------------- GEMM (K=128 fixed), fp32 compute ----------------
template <int OC, int RPT, int OUT_BF16>
__global__ __launch_bounds__(256) void k_gemm(const float* __restrict__ A,
                                              const float* __restrict__ W,
                                              void* __restrict__ outp,
                                              int nrows) {
    constexpr int CG   = OC / 4;
    constexpr int RG   = 256 / CG;
    constexpr int ROWS = RG * RPT;   // 64
    constexpr int LDSP = 128 + 4;
    __shared__ float xs[ROWS][LDSP];

    const int tid  = threadIdx.x;
    const int row0 = blockIdx.x * ROWS;

    for (int idx = tid; idx < ROWS * 32; idx += 256) {
        int r = idx >> 5, c4 = idx & 31;
        int gr = row0 + r;
        if (gr >= nrows) gr = nrows - 1;
        float4 v = ((const float4*)(A + (size_t)gr * 128))[c4];
        float* dp = &xs[r][c4 * 4];
        dp[0] = v.x; dp[1] = v.y; dp[2] = v.z; dp[3] = v.w;
    }
    __syncthreads();

    const int cg = tid % CG;
    const int rg = tid / CG;

    float acc[RPT][4];
    #pragma unroll
    for (int r = 0; r < RPT; r++) acc[r][0] = acc[r][1] = acc[r][2] = acc[r][3] = 0.f;

    const float* Wp = W + cg * 4;
    for (int k = 0; k < 128; k += 4) {
        float4 w0 = *(const float4*)(Wp + (size_t)(k + 0) * OC);
        float4 w1 = *(const float4*)(Wp + (size_t)(k + 1) * OC);
        float4 w2 = *(const float4*)(Wp + (size_t)(k + 2) * OC);
        float4 w3 = *(const float4*)(Wp + (size_t)(k + 3) * OC);
        #pragma unroll
        for (int r = 0; r < RPT; r++) {
            float4 xv = *(const float4*)&xs[rg * RPT + r][k];
            acc[r][0] = fmaf(xv.w, w3.x, fmaf(xv.z, w2.x, fmaf(xv.y, w1.x, fmaf(xv.x, w0.x, acc[r][0]))));
            acc[r][1] = fmaf(xv.w, w3.y, fmaf(xv.z, w2.y, fmaf(xv.y, w1.y, fmaf(xv.x, w0.y, acc[r][1]))));
            acc[r][2] = fmaf(xv.w, w3.z, fmaf(xv.z, w2.z, fmaf(xv.y, w1.z, fmaf(xv.x, w0.z, acc[r][2]))));
            acc[r][3] = fmaf(xv.w, w3.w, fmaf(xv.z, w2.w, fmaf(xv.y, w1.w, fmaf(xv.x, w0.w, acc[r][3]))));
        }
    }

    #pragma unroll
    for (int r = 0; r < RPT; r++) {
        int gr = row0 + rg * RPT + r;
        if (gr < nrows) {
            if (OUT_BF16) {
                unsigned int p0 = (unsigned int)f2bf(acc[r][0]) | ((unsigned int)f2bf(acc[r][1]) << 16);
                unsigned int p1 = (unsigned int)f2bf(acc[r][2]) | ((unsigned int)f2bf(acc[r][3]) << 16);
                uint2* o = (uint2*)outp;
                o[(size_t)gr * (OC / 4) + cg] = make_uint2(p0, p1);
            } else {
                float4 o = make_float4(acc[r][0], acc[r][1], acc[r][2], acc[r][3]);
                *(float4*)((float*)outp + (size_t)gr * OC + cg * 4) = o;
            }
        }
    }
}

// ---------------- Aggregation ----------------
__global__ __launch_bounds__(256) void k_agg128bf(const unsigned int* __restrict__ hb,
                                                  const int* __restrict__ rowptr,
                                                  const int* __restrict__ srcs,
                                                  const float* __restrict__ dinv,
                                                  const float* __restrict__ bias,
                                                  float* __restrict__ out,
                                                  int relu) {
    const int l = threadIdx.x & 63;
    const int wv0 = blockIdx.x * 4 + (threadIdx.x >> 6);
    const float2 bv = ((const float2*)bias)[l];

    for (int i = wv0; i < N_NODES; i += AGG_BLOCKS * 4) {
        const float di = dinv[i];
        unsigned int svv = hb[(size_t)i * 64 + l];
        const float sw = di * di;
        float2 acc;
        acc.x = bfbits2f(svv & 0xFFFFu) * sw;
        acc.y = bfbits2f(svv >> 16) * sw;

        const int start = rowptr[i], end = rowptr[i + 1];
        for (int b = start; b < end; b += 64) {
            const int eb = min(end - b, 64);
            int s = 0; float w = 0.f;
            if (l < eb) { s = srcs[b + l]; w = dinv[s] * di; }
            int j = 0;
            for (; j + 8 <= eb; j += 8) {
                int   si[8]; float wi[8];
                #pragma unroll
                for (int u = 0; u < 8; u++) { si[u] = __shfl(s, j + u); wi[u] = __shfl(w, j + u); }
                unsigned int v[8];
                #pragma unroll
                for (int u = 0; u < 8; u++) v[u] = hb[(size_t)si[u] * 64 + l];
                #pragma unroll
                for (int u = 0; u < 8; u++) {
                    acc.x = fmaf(bfbits2f(v[u] & 0xFFFFu), wi[u], acc.x);
                    acc.y = fmaf(bfbits2f(v[u] >> 16),     wi[u], acc.y);
                }
            }
            for (; j < eb; j++) {
                const int   sj = __shfl(s, j);
                const float wj = __shfl(w, j);
                unsigned int v = hb[(size_t)sj * 64 + l];
                acc.x = fmaf(bfbits2f(v & 0xFFFFu), wj, acc.x);
                acc.y = fmaf(bfbits2f(v >> 16),     wj, acc.y);
            }
        }
        acc.x += bv.x; acc.y += bv.y;
        if (relu) { acc.x = fmaxf(acc.x, 0.f); acc.y = fmaxf(acc.y, 0.f); }
        ((float2*)out)[(size_t)i * 64 + l] = acc;
    }
}

__global__ __launch_bounds__(256) void k_agg64bf(const unsigned short* __restrict__ hb,
                                                 const int* __restrict__ rowptr,
                                                 const int* __restrict__ srcs,
                                                 const float* __restrict__ dinv,
                                                 const float* __restrict__ bias,
                                                 float* __restrict__ out,
                                                 int relu) {
    const int l = threadIdx.x & 63;
    const int wv0 = blockIdx.x * 4 + (threadIdx.x >> 6);
    const float bi = bias[l];

    for (int i = wv0; i < N_NODES; i += AGG_BLOCKS * 4) {
        const float di = dinv[i];
        float acc = bfbits2f((unsigned int)hb[(size_t)i * 64 + l]) * (di * di);

        const int start = rowptr[i], end = rowptr[i + 1];
        for (int b = start; b < end; b += 64) {
            const int eb = min(end - b, 64);
            int s = 0; float w = 0.f;
            if (l < eb) { s = srcs[b + l]; w = dinv[s] * di; }
            int j = 0;
            for (; j + 8 <= eb; j += 8) {
                int   si[8]; float wi[8];
                #pragma unroll
                for (int u = 0; u < 8; u++) { si[u] = __shfl(s, j + u); wi[u] = __shfl(w, j + u); }
                unsigned short v[8];
                #pragma unroll
                for (int u = 0; u < 8; u++) v[u] = hb[(size_t)si[u] * 64 + l];
                #pragma unroll
                for (int u = 0; u < 8; u++) acc = fmaf(bfbits2f((unsigned int)v[u]), wi[u], acc);
            }
            for (; j < eb; j++) {
                const int   sj = __shfl(s, j);
                const float wj = __shfl(w, j);
                acc = fmaf(bfbits2f((unsigned int)hb[(size_t)sj * 64 + l]), wj, acc);
            }
        }
        acc += bi;
        if (relu) acc = fmaxf(acc, 0.f);
        out[(size_t)i * 64 + l] = acc;
    }
}

// ---------------- launch ----------------

extern "C" void kernel_launch(void* const* d_in, const int* in_sizes, int n_in,
                              void* d_out, int out_size, void* d_ws, size_t ws_size,
                              hipStream_t stream) {
    const float* x  = (const float*)d_in[0];
    const int*   ei = (const int*)d_in[1];
    const float* W1 = (const float*)d_in[2];
    const float* b1 = (const float*)d_in[3];
    const float* W2 = (const float*)d_in[4];
    const float* b2 = (const float*)d_in[5];
    float* out = (float*)d_out;

    char* p = (char*)d_ws;
    size_t used = 0;
    auto alloc = [&](size_t bytes) {
        void* q = (void*)p;
        size_t pad = (bytes + 255) & ~(size_t)255;
        p += pad;
        used += pad;
        return q;
    };
    int*   deg    = (int*)alloc(sizeof(int) * N_NODES);
    int*   rowptr = (int*)alloc(sizeof(int) * (N_NODES + 1));
    int*   cursor = (int*)alloc(sizeof(int) * N_NODES);
    float* dinv   = (float*)alloc(sizeof(float) * N_NODES);
    int*   bsum   = (int*)alloc(sizeof(int) * NBLK);
    int*   gcur   = (int*)alloc(sizeof(int) * SH);
    int*   srcs   = (int*)alloc(sizeof(int) * N_EDGES);
    // region A: buckets (13.4MB) then h1b (25.6MB) — buckets dead before gemm1 writes h1b
    void*  regA   = alloc(sizeof(unsigned int) * (size_t)N_NODES * 64);  // 25.6MB
    int2*  buckets = (int2*)regA;
    unsigned int* h1b = (unsigned int*)regA;
    float* agg1   = (float*)alloc(sizeof(float) * (size_t)N_NODES * HID_CH);
    unsigned short* h2b = (unsigned short*)alloc(sizeof(unsigned short) * (size_t)N_NODES * 64);

    if (used > ws_size) return;

    hipMemsetAsync(deg, 0, sizeof(int) * N_NODES, stream);
    hipMemsetAsync(gcur, 0, sizeof(int) * SH, stream);
    k_bucket<<<FILL_NCHUNK, 256, 0, stream>>>(ei, gcur, buckets);
    k_countB<<<P2_GRID, 256, 0, stream>>>(buckets, gcur, deg);
    ks1<<<NBLK, 256, 0, stream>>>(deg, rowptr, bsum);
    ks2<<<1, 512, 0, stream>>>(bsum, rowptr);
    ks3<<<NBLK, 256, 0, stream>>>(deg, rowptr, cursor, dinv, bsum);
    k_fillB<<<P2_GRID, 256, 0, stream>>>(buckets, gcur, cursor, srcs);

    k_gemm<128, 8, 1><<<(N_NODES + 63) / 64, 256, 0, stream>>>(x, W1, (void*)h1b, N_NODES);
    k_agg128bf<<<AGG_BLOCKS, 256, 0, stream>>>(h1b, rowptr, srcs, dinv, b1, agg1, 1);
    k_gemm<64, 4, 1><<<(N_NODES + 63) / 64, 256, 0, stream>>>(agg1, W2, (void*)h2b, N_NODES);
    k_agg64bf<<<AGG_BLOCKS, 256, 0, stream>>>(h2b, rowptr, srcs, dinv, b2, out, 0);
}

// Round 7
// 232.130 us; speedup vs baseline: 1.6142x; 1.6142x over previous
//
#include <hip/hip_runtime.h>
#include <cstdint>
#include <cstddef>

#define N_NODES 100000
#define N_EDGES 1600000
#define IN_CH   128
#define HID_CH  128
#define OUT_CH  64

#define FILL_CHUNK 2048
#define FILL_NCHUNK ((N_EDGES + FILL_CHUNK - 1) / FILL_CHUNK)  // 782
#define AGG_BLOCKS 2048

#define SH64   64
#define SHR64  1563      // ceil(100000/64); 64*1563 = 100032
#define BCAP64 27000     // mean 25008, sigma ~157 -> 12.7 sigma slack

__device__ __forceinline__ unsigned short f2bf(float f) {
    unsigned int u = __float_as_uint(f);
    unsigned int r = (u + 0x7FFFu + ((u >> 16) & 1u)) >> 16;   // RNE
    return (unsigned short)r;
}
__device__ __forceinline__ float bfbits2f(unsigned int lo16) {
    return __uint_as_float(lo16 << 16);
}

typedef __attribute__((ext_vector_type(8))) short bf16x8;
typedef __attribute__((ext_vector_type(4))) float f32x4;

// ---------------- CSR build ----------------
// Pass 1: read ei once, bucket (src,dst) pairs into 64 dst-ranges.
// Only 64 global atomics per block (range-base reservation); per-edge
// ranking is LDS-scope.
__global__ __launch_bounds__(256) void k_bucket64(const int* __restrict__ ei,
                                                  int* __restrict__ gcur,
                                                  long long* __restrict__ buckets) {
    __shared__ int scount[SH64];
    __shared__ int sbase[SH64];
    const int tid  = threadIdx.x;
    const int base = blockIdx.x * FILL_CHUNK;
    if (tid < SH64) scount[tid] = 0;
    __syncthreads();
    int dv[8], sv[8], shd[8], rk[8];
    #pragma unroll
    for (int k = 0; k < 8; k++) {
        int e = base + k * 256 + tid;
        if (e < N_EDGES) {
            dv[k] = __builtin_nontemporal_load(ei + N_EDGES + e);
            sv[k] = __builtin_nontemporal_load(ei + e);
            shd[k] = dv[k] / SHR64;
            rk[k] = atomicAdd(&scount[shd[k]], 1);     // LDS atomic
        } else shd[k] = -1;
    }
    __syncthreads();
    if (tid < SH64) sbase[tid] = atomicAdd(&gcur[tid], scount[tid]);
    __syncthreads();
    #pragma unroll
    for (int k = 0; k < 8; k++) {
        if (shd[k] >= 0) {
            int pos = sbase[shd[k]] + rk[k];
            if (pos < BCAP64)
                buckets[(size_t)shd[k] * BCAP64 + pos] =
                    ((long long)sv[k] << 32) | (unsigned int)dv[k];
        }
    }
}

// Exclusive scan of the 64 range totals (single wave).
__global__ void k_scan64(const int* __restrict__ gcur, int* __restrict__ rbase,
                         int* __restrict__ rowptr) {
    int l = threadIdx.x & 63;
    int v = gcur[l];
    int x = v;
    #pragma unroll
    for (int d = 1; d < 64; d <<= 1) {
        int y = __shfl_up(x, d, 64);
        if (l >= d) x += y;
    }
    rbase[l] = x - v;
    if (l == 63) { rbase[64] = x; rowptr[N_NODES] = x; }
}

// Pass 2: one block per range. Histogram -> LDS scan -> rowptr/dinv ->
// scatter srcs. ALL per-edge atomics are LDS-scope.
__global__ __launch_bounds__(1024) void k_build(const long long* __restrict__ buckets,
                                                const int* __restrict__ gcur,
                                                const int* __restrict__ rbase,
                                                int* __restrict__ rowptr,
                                                float* __restrict__ dinv,
                                                int* __restrict__ srcs) {
    __shared__ int hist[1600];
    __shared__ int wsum[16];
    const int s  = blockIdx.x;
    const int lo = s * SHR64;
    const int nb = min(SHR64, N_NODES - lo);
    const int n  = min(gcur[s], BCAP64);
    const int gbase = rbase[s];
    const int t = threadIdx.x, lane = t & 63, wid = t >> 6;
    const long long* bp = buckets + (size_t)s * BCAP64;

    for (int i = t; i < 1600; i += 1024) hist[i] = 0;
    __syncthreads();
    for (int i = t; i < n; i += 1024) {
        int d = (int)bp[i];                  // normal load: slice stays L2-hot for pass 2
        atomicAdd(&hist[d - lo], 1);
    }
    __syncthreads();

    // block-wide exclusive scan of hist[0..1600) in 2 chunks of 1024
    int carry = 0;
    for (int c = 0; c < 1600; c += 1024) {
        int idx = c + t;
        int v = (idx < 1600) ? hist[idx] : 0;
        int x = v;
        #pragma unroll
        for (int d = 1; d < 64; d <<= 1) {
            int y = __shfl_up(x, d, 64);
            if (lane >= d) x += y;
        }
        if (lane == 63) wsum[wid] = x;
        __syncthreads();
        if (wid == 0) {
            int sv = (lane < 16) ? wsum[lane] : 0;
            #pragma unroll
            for (int d = 1; d < 16; d <<= 1) {
                int y = __shfl_up(sv, d, 64);
                if (lane >= d) sv += y;
            }
            if (lane < 16) wsum[lane] = sv;
        }
        __syncthreads();
        int woff = (wid == 0) ? 0 : wsum[wid - 1];
        int excl = carry + woff + (x - v);
        if (idx < nb) {
            rowptr[lo + idx] = gbase + excl;
            dinv[lo + idx]   = rsqrtf((float)(v + 1));   // +1 self-loop
        }
        if (idx < 1600) hist[idx] = excl;                 // becomes cursor
        carry += wsum[15];
        __syncthreads();
    }

    for (int i = t; i < n; i += 1024) {
        long long v = bp[i];
        int d  = (int)v;
        int sv = (int)(v >> 32);
        int pos = atomicAdd(&hist[d - lo], 1);            // LDS cursor
        srcs[gbase + pos] = sv;
    }
}

// ---------------- GEMM: bf16 MFMA (16x16x32), K=128 single residency ----------------
// Block 256 = 4 waves; tile 128 rows x OC cols. A fp32->bf16 staged swizzled;
// W staged transposed (Wt[c][k]) so B-frags are contiguous ds_read_b128.
// Swizzle (ushort units): idx ^ ((row&7)<<3) -> uniform 8 lanes/bank-quad
// (structural floor for b128). Output packed bf16 (the gather table).
template <int OC>
__global__ __launch_bounds__(256) void k_gemm_mfma(const float* __restrict__ A,
                                                   const float* __restrict__ W,
                                                   unsigned short* __restrict__ hb) {
    __shared__ unsigned short As[128 * 128];
    __shared__ unsigned short Ws[OC * 128];
    const int tid = threadIdx.x;
    const int l   = tid & 63;
    const int wv  = tid >> 6;
    const int row0 = blockIdx.x * 128;

    #pragma unroll
    for (int it = 0; it < 16; it++) {
        int idx4 = it * 256 + tid;            // 4096 float4 loads
        int r = idx4 >> 5, c4 = idx4 & 31;
        int gr = row0 + r; if (gr >= N_NODES) gr = N_NODES - 1;
        float4 v = ((const float4*)(A + (size_t)gr * 128))[c4];
        int bi = (r * 128 + c4 * 4) ^ ((r & 7) << 3);
        ushort4 pk;
        pk.x = f2bf(v.x); pk.y = f2bf(v.y); pk.z = f2bf(v.z); pk.w = f2bf(v.w);
        *(ushort4*)&As[bi] = pk;
    }
    for (int idx = tid; idx < 128 * OC; idx += 256) {
        int k = idx / OC, c = idx % OC;       // W[k][c], coalesced
        Ws[(c * 128 + k) ^ ((c & 7) << 3)] = f2bf(W[idx]);
    }
    __syncthreads();

    constexpr int NCF = OC / 16;
    f32x4 acc[2][NCF];
    #pragma unroll
    for (int a = 0; a < 2; a++)
        #pragma unroll
        for (int b = 0; b < NCF; b++) acc[a][b] = {0.f, 0.f, 0.f, 0.f};

    const int fr = l & 15;     // A row / B col within frag
    const int g  = l >> 6 == 0 ? (l >> 4) : 0; // l>>4 (0..3), k-subgroup
    const int kg = (l >> 4) * 8;

    #pragma unroll
    for (int ks = 0; ks < 4; ks++) {
        const int kk = ks * 32 + kg;
        bf16x8 a0, a1;
        {
            int r = wv * 32 + fr;
            a0 = *(const bf16x8*)&As[(r * 128 + kk) ^ ((r & 7) << 3)];
            r += 16;
            a1 = *(const bf16x8*)&As[(r * 128 + kk) ^ ((r & 7) << 3)];
        }
        #pragma unroll
        for (int cf = 0; cf < NCF; cf++) {
            int c = cf * 16 + fr;
            bf16x8 b = *(const bf16x8*)&Ws[(c * 128 + kk) ^ ((c & 7) << 3)];
            acc[0][cf] = __builtin_amdgcn_mfma_f32_16x16x32_bf16(a0, b, acc[0][cf], 0, 0, 0);
            acc[1][cf] = __builtin_amdgcn_mfma_f32_16x16x32_bf16(a1, b, acc[1][cf], 0, 0, 0);
        }
    }

    // C/D mapping (m89-verified): col = lane&15, row = (lane>>4)*4 + reg
    const int g4 = (l >> 4) * 4;
    #pragma unroll
    for (int rf = 0; rf < 2; rf++) {
        #pragma unroll
        for (int cf = 0; cf < NCF; cf++) {
            #pragma unroll
            for (int r = 0; r < 4; r++) {
                int grow = row0 + wv * 32 + rf * 16 + g4 + r;
                if (grow < N_NODES)
                    hb[(size_t)grow * OC + cf * 16 + fr] = f2bf(acc[rf][cf][r]);
            }
        }
    }
}

// ---------------- Aggregation (unchanged from R6) ----------------
__global__ __launch_bounds__(256) void k_agg128bf(const unsigned int* __restrict__ hb,
                                                  const int* __restrict__ rowptr,
                                                  const int* __restrict__ srcs,
                                                  const float* __restrict__ dinv,
                                                  const float* __restrict__ bias,
                                                  float* __restrict__ out,
                                                  int relu) {
    const int l = threadIdx.x & 63;
    const int wv0 = blockIdx.x * 4 + (threadIdx.x >> 6);
    const float2 bv = ((const float2*)bias)[l];

    for (int i = wv0; i < N_NODES; i += AGG_BLOCKS * 4) {
        const float di = dinv[i];
        unsigned int svv = hb[(size_t)i * 64 + l];
        const float sw = di * di;
        float2 acc;
        acc.x = bfbits2f(svv & 0xFFFFu) * sw;
        acc.y = bfbits2f(svv >> 16) * sw;

        const int start = rowptr[i], end = rowptr[i + 1];
        for (int b = start; b < end; b += 64) {
            const int eb = min(end - b, 64);
            int s = 0; float w = 0.f;
            if (l < eb) { s = srcs[b + l]; w = dinv[s] * di; }
            int j = 0;
            for (; j + 8 <= eb; j += 8) {
                int   si[8]; float wi[8];
                #pragma unroll
                for (int u = 0; u < 8; u++) { si[u] = __shfl(s, j + u); wi[u] = __shfl(w, j + u); }
                unsigned int v[8];
                #pragma unroll
                for (int u = 0; u < 8; u++) v[u] = hb[(size_t)si[u] * 64 + l];
                #pragma unroll
                for (int u = 0; u < 8; u++) {
                    acc.x = fmaf(bfbits2f(v[u] & 0xFFFFu), wi[u], acc.x);
                    acc.y = fmaf(bfbits2f(v[u] >> 16),     wi[u], acc.y);
                }
            }
            for (; j < eb; j++) {
                const int   sj = __shfl(s, j);
                const float wj = __shfl(w, j);
                unsigned int v = hb[(size_t)sj * 64 + l];
                acc.x = fmaf(bfbits2f(v & 0xFFFFu), wj, acc.x);
                acc.y = fmaf(bfbits2f(v >> 16),     wj, acc.y);
            }
        }
        acc.x += bv.x; acc.y += bv.y;
        if (relu) { acc.x = fmaxf(acc.x, 0.f); acc.y = fmaxf(acc.y, 0.f); }
        ((float2*)out)[(size_t)i * 64 + l] = acc;
    }
}

__global__ __launch_bounds__(256) void k_agg64bf(const unsigned short* __restrict__ hb,
                                                 const int* __restrict__ rowptr,
                                                 const int* __restrict__ srcs,
                                                 const float* __restrict__ dinv,
                                                 const float* __restrict__ bias,
                                                 float* __restrict__ out,
                                                 int relu) {
    const int l = threadIdx.x & 63;
    const int wv0 = blockIdx.x * 4 + (threadIdx.x >> 6);
    const float bi = bias[l];

    for (int i = wv0; i < N_NODES; i += AGG_BLOCKS * 4) {
        const float di = dinv[i];
        float acc = bfbits2f((unsigned int)hb[(size_t)i * 64 + l]) * (di * di);

        const int start = rowptr[i], end = rowptr[i + 1];
        for (int b = start; b < end; b += 64) {
            const int eb = min(end - b, 64);
            int s = 0; float w = 0.f;
            if (l < eb) { s = srcs[b + l]; w = dinv[s] * di; }
            int j = 0;
            for (; j + 8 <= eb; j += 8) {
                int   si[8]; float wi[8];
                #pragma unroll
                for (int u = 0; u < 8; u++) { si[u] = __shfl(s, j + u); wi[u] = __shfl(w, j + u); }
                unsigned short v[8];
                #pragma unroll
                for (int u = 0; u < 8; u++) v[u] = hb[(size_t)si[u] * 64 + l];
                #pragma unroll
                for (int u = 0; u < 8; u++) acc = fmaf(bfbits2f((unsigned int)v[u]), wi[u], acc);
            }
            for (; j < eb; j++) {
                const int   sj = __shfl(s, j);
                const float wj = __shfl(w, j);
                acc = fmaf(bfbits2f((unsigned int)hb[(size_t)sj * 64 + l]), wj, acc);
            }
        }
        acc += bi;
        if (relu) acc = fmaxf(acc, 0.f);
        out[(size_t)i * 64 + l] = acc;
    }
}

// ---------------- launch ----------------

extern "C" void kernel_launch(void* const* d_in, const int* in_sizes, int n_in,
                              void* d_out, int out_size, void* d_ws, size_t ws_size,
                              hipStream_t stream) {
    const float* x  = (const float*)d_in[0];
    const int*   ei = (const int*)d_in[1];
    const float* W1 = (const float*)d_in[2];
    const float* b1 = (const float*)d_in[3];
    const float* W2 = (const float*)d_in[4];
    const float* b2 = (const float*)d_in[5];
    float* out = (float*)d_out;

    char* p = (char*)d_ws;
    size_t used = 0;
    auto alloc = [&](size_t bytes) {
        void* q = (void*)p;
        size_t pad = (bytes + 255) & ~(size_t)255;
        p += pad;
        used += pad;
        return q;
    };
    int*   rowptr = (int*)alloc(sizeof(int) * (N_NODES + 1));
    float* dinv   = (float*)alloc(sizeof(float) * N_NODES);
    int*   gcur   = (int*)alloc(sizeof(int) * SH64);
    int*   rbase  = (int*)alloc(sizeof(int) * (SH64 + 1));
    int*   srcs   = (int*)alloc(sizeof(int) * N_EDGES);
    // region A: buckets (13.8MB) then h1b (25.6MB) — buckets dead before gemm1
    void*  regA   = alloc(sizeof(unsigned short) * (size_t)N_NODES * 128);  // 25.6MB
    long long* buckets = (long long*)regA;
    unsigned short* h1b = (unsigned short*)regA;
    float* agg1   = (float*)alloc(sizeof(float) * (size_t)N_NODES * HID_CH);
    unsigned short* h2b = (unsigned short*)alloc(sizeof(unsigned short) * (size_t)N_NODES * 64);

    if (used > ws_size) return;

    hipMemsetAsync(gcur, 0, sizeof(int) * SH64, stream);
    k_bucket64<<<FILL_NCHUNK, 256, 0, stream>>>(ei, gcur, buckets);
    k_scan64<<<1, 64, 0, stream>>>(gcur, rbase, rowptr);
    k_build<<<SH64, 1024, 0, stream>>>(buckets, gcur, rbase, rowptr, dinv, srcs);

    k_gemm_mfma<128><<<(N_NODES + 127) / 128, 256, 0, stream>>>(x, W1, h1b);
    k_agg128bf<<<AGG_BLOCKS, 256, 0, stream>>>((const unsigned int*)h1b, rowptr, srcs, dinv, b1, agg1, 1);
    k_gemm_mfma<64><<<(N_NODES + 127) / 128, 256, 0, stream>>>(agg1, W2, h2b);
    k_agg64bf<<<AGG_BLOCKS, 256, 0, stream>>>(h2b, rowptr, srcs, dinv, b2, out, 0);
}

// Round 8
// 223.756 us; speedup vs baseline: 1.6746x; 1.0374x over previous
//
#include <hip/hip_runtime.h>
#include <cstdint>
#include <cstddef>

#define N_NODES 100000
#define N_EDGES 1600000
#define IN_CH   128
#define HID_CH  128
#define OUT_CH  64

#define FILL_CHUNK 2048
#define FILL_NCHUNK ((N_EDGES + FILL_CHUNK - 1) / FILL_CHUNK)  // 782
#define AGG_BLOCKS 2048

#define SH64   64
#define SHR64  1563      // ceil(100000/64)
#define BCAP64 27000     // mean 25008, ~12.7 sigma slack

__device__ __forceinline__ unsigned short f2bf(float f) {
    unsigned int u = __float_as_uint(f);
    unsigned int r = (u + 0x7FFFu + ((u >> 16) & 1u)) >> 16;   // RNE
    return (unsigned short)r;
}
__device__ __forceinline__ float bfbits2f(unsigned int lo16) {
    return __uint_as_float(lo16 << 16);
}

typedef __attribute__((ext_vector_type(8))) short bf16x8;
typedef __attribute__((ext_vector_type(4))) float f32x4;

// ---------------- CSR build ----------------
// Pass 1: bucket (src,dst) into 64 dst-ranges. Per-wave sub-histograms cut
// LDS-atomic contention 4x; 64 global atomics per block.
__global__ __launch_bounds__(256) void k_bucket64(const int* __restrict__ ei,
                                                  int* __restrict__ gcur,
                                                  long long* __restrict__ buckets) {
    __shared__ int scount[4][SH64];
    __shared__ int sbase[4][SH64];
    const int tid  = threadIdx.x;
    const int w    = tid >> 6;
    const int base = blockIdx.x * FILL_CHUNK;
    scount[tid >> 6][tid & 63] = 0;
    __syncthreads();
    int dv[8], sv[8], shd[8], rk[8];
    #pragma unroll
    for (int k = 0; k < 8; k++) {
        int e = base + k * 256 + tid;
        if (e < N_EDGES) {
            dv[k] = __builtin_nontemporal_load(ei + N_EDGES + e);
            sv[k] = __builtin_nontemporal_load(ei + e);
            shd[k] = dv[k] / SHR64;
            rk[k] = atomicAdd(&scount[w][shd[k]], 1);   // wave-private bin
        } else shd[k] = -1;
    }
    __syncthreads();
    if (tid < SH64) {
        int c0 = scount[0][tid], c1 = scount[1][tid];
        int c2 = scount[2][tid], c3 = scount[3][tid];
        int gb = atomicAdd(&gcur[tid], c0 + c1 + c2 + c3);
        sbase[0][tid] = gb;
        sbase[1][tid] = gb + c0;
        sbase[2][tid] = gb + c0 + c1;
        sbase[3][tid] = gb + c0 + c1 + c2;
    }
    __syncthreads();
    #pragma unroll
    for (int k = 0; k < 8; k++) {
        if (shd[k] >= 0) {
            int pos = sbase[w][shd[k]] + rk[k];
            if (pos < BCAP64)
                buckets[(size_t)shd[k] * BCAP64 + pos] =
                    ((long long)sv[k] << 32) | (unsigned int)dv[k];
        }
    }
}

// Pass 2: one block per range. In-block gcur prefix scan (replaces k_scan64),
// histogram -> LDS scan -> rowptr/dinv -> scatter. Per-edge atomics LDS-scope.
__global__ __launch_bounds__(1024) void k_build(const long long* __restrict__ buckets,
                                                const int* __restrict__ gcur,
                                                int* __restrict__ rowptr,
                                                float* __restrict__ dinv,
                                                int* __restrict__ srcs) {
    __shared__ int hist[1600];
    __shared__ int wsum[16];
    __shared__ int sgbase;
    const int s  = blockIdx.x;
    const int lo = s * SHR64;
    const int nb = min(SHR64, N_NODES - lo);
    const int n  = min(gcur[s], BCAP64);
    const int t = threadIdx.x, lane = t & 63, wid = t >> 6;
    const long long* bp = buckets + (size_t)s * BCAP64;

    if (t < SH64) {                       // wave 0: prefix over range totals
        int v = gcur[t];
        int x = v;
        #pragma unroll
        for (int d = 1; d < 64; d <<= 1) {
            int y = __shfl_up(x, d, 64);
            if (t >= d) x += y;
        }
        if (t == s) sgbase = x - v;
        if (s == SH64 - 1 && t == SH64 - 1) rowptr[N_NODES] = x;
    }
    for (int i = t; i < 1600; i += 1024) hist[i] = 0;
    __syncthreads();
    const int gbase = sgbase;

    for (int i = t; i < n; i += 1024) {
        int d = (int)bp[i];
        atomicAdd(&hist[d - lo], 1);
    }
    __syncthreads();

    int carry = 0;
    for (int c = 0; c < 1600; c += 1024) {
        int idx = c + t;
        int v = (idx < 1600) ? hist[idx] : 0;
        int x = v;
        #pragma unroll
        for (int d = 1; d < 64; d <<= 1) {
            int y = __shfl_up(x, d, 64);
            if (lane >= d) x += y;
        }
        if (lane == 63) wsum[wid] = x;
        __syncthreads();
        if (wid == 0) {
            int sv = (lane < 16) ? wsum[lane] : 0;
            #pragma unroll
            for (int d = 1; d < 16; d <<= 1) {
                int y = __shfl_up(sv, d, 64);
                if (lane >= d) sv += y;
            }
            if (lane < 16) wsum[lane] = sv;
        }
        __syncthreads();
        int woff = (wid == 0) ? 0 : wsum[wid - 1];
        int excl = carry + woff + (x - v);
        if (idx < nb) {
            rowptr[lo + idx] = gbase + excl;
            dinv[lo + idx]   = rsqrtf((float)(v + 1));   // +1 self-loop
        }
        if (idx < 1600) hist[idx] = excl;                 // becomes cursor
        carry += wsum[15];
        __syncthreads();
    }

    for (int i = t; i < n; i += 1024) {
        long long v = bp[i];
        int d  = (int)v;
        int sv = (int)(v >> 32);
        int pos = atomicAdd(&hist[d - lo], 1);
        srcs[gbase + pos] = sv;
    }
}

// ---------------- GEMM: bf16 MFMA (16x16x32), K=128 single residency ----------------
// fp32-input variant (gemm1). Swizzle (ushort units): idx ^ ((row&7)<<3).
template <int OC>
__global__ __launch_bounds__(256) void k_gemm_mfma(const float* __restrict__ A,
                                                   const float* __restrict__ W,
                                                   unsigned short* __restrict__ hb) {
    __shared__ unsigned short As[128 * 128];
    __shared__ unsigned short Ws[OC * 128];
    const int tid = threadIdx.x;
    const int l   = tid & 63;
    const int wv  = tid >> 6;
    const int row0 = blockIdx.x * 128;

    #pragma unroll
    for (int it = 0; it < 16; it++) {
        int idx4 = it * 256 + tid;
        int r = idx4 >> 5, c4 = idx4 & 31;
        int gr = row0 + r; if (gr >= N_NODES) gr = N_NODES - 1;
        float4 v = ((const float4*)(A + (size_t)gr * 128))[c4];
        int bi = (r * 128 + c4 * 4) ^ ((r & 7) << 3);
        ushort4 pk;
        pk.x = f2bf(v.x); pk.y = f2bf(v.y); pk.z = f2bf(v.z); pk.w = f2bf(v.w);
        *(ushort4*)&As[bi] = pk;
    }
    for (int idx = tid; idx < 128 * OC; idx += 256) {
        int k = idx / OC, c = idx % OC;
        Ws[(c * 128 + k) ^ ((c & 7) << 3)] = f2bf(W[idx]);
    }
    __syncthreads();

    constexpr int NCF = OC / 16;
    f32x4 acc[2][NCF];
    #pragma unroll
    for (int a = 0; a < 2; a++)
        #pragma unroll
        for (int b = 0; b < NCF; b++) acc[a][b] = {0.f, 0.f, 0.f, 0.f};

    const int fr = l & 15;
    const int kg = (l >> 4) * 8;

    #pragma unroll
    for (int ks = 0; ks < 4; ks++) {
        const int kk = ks * 32 + kg;
        bf16x8 a0, a1;
        {
            int r = wv * 32 + fr;
            a0 = *(const bf16x8*)&As[(r * 128 + kk) ^ ((r & 7) << 3)];
            r += 16;
            a1 = *(const bf16x8*)&As[(r * 128 + kk) ^ ((r & 7) << 3)];
        }
        #pragma unroll
        for (int cf = 0; cf < NCF; cf++) {
            int c = cf * 16 + fr;
            bf16x8 b = *(const bf16x8*)&Ws[(c * 128 + kk) ^ ((c & 7) << 3)];
            acc[0][cf] = __builtin_amdgcn_mfma_f32_16x16x32_bf16(a0, b, acc[0][cf], 0, 0, 0);
            acc[1][cf] = __builtin_amdgcn_mfma_f32_16x16x32_bf16(a1, b, acc[1][cf], 0, 0, 0);
        }
    }

    const int g4 = (l >> 4) * 4;
    #pragma unroll
    for (int rf = 0; rf < 2; rf++)
        #pragma unroll
        for (int cf = 0; cf < NCF; cf++)
            #pragma unroll
            for (int r = 0; r < 4; r++) {
                int grow = row0 + wv * 32 + rf * 16 + g4 + r;
                if (grow < N_NODES)
                    hb[(size_t)grow * OC + cf * 16 + fr] = f2bf(acc[rf][cf][r]);
            }
}

// bf16-input variant (gemm2: A already bf16-packed).
template <int OC>
__global__ __launch_bounds__(256) void k_gemm_mfma_b(const unsigned short* __restrict__ A,
                                                     const float* __restrict__ W,
                                                     unsigned short* __restrict__ hb) {
    __shared__ unsigned short As[128 * 128];
    __shared__ unsigned short Ws[OC * 128];
    const int tid = threadIdx.x;
    const int l   = tid & 63;
    const int wv  = tid >> 6;
    const int row0 = blockIdx.x * 128;

    #pragma unroll
    for (int it = 0; it < 8; it++) {
        int idx8 = it * 256 + tid;          // 2048 x 16B
        int r = idx8 >> 4, c8 = idx8 & 15;
        int gr = row0 + r; if (gr >= N_NODES) gr = N_NODES - 1;
        uint4 v = ((const uint4*)(A + (size_t)gr * 128))[c8];
        int bi = (r * 128 + c8 * 8) ^ ((r & 7) << 3);
        *(uint4*)&As[bi] = v;
    }
    for (int idx = tid; idx < 128 * OC; idx += 256) {
        int k = idx / OC, c = idx % OC;
        Ws[(c * 128 + k) ^ ((c & 7) << 3)] = f2bf(W[idx]);
    }
    __syncthreads();

    constexpr int NCF = OC / 16;
    f32x4 acc[2][NCF];
    #pragma unroll
    for (int a = 0; a < 2; a++)
        #pragma unroll
        for (int b = 0; b < NCF; b++) acc[a][b] = {0.f, 0.f, 0.f, 0.f};

    const int fr = l & 15;
    const int kg = (l >> 4) * 8;

    #pragma unroll
    for (int ks = 0; ks < 4; ks++) {
        const int kk = ks * 32 + kg;
        bf16x8 a0, a1;
        {
            int r = wv * 32 + fr;
            a0 = *(const bf16x8*)&As[(r * 128 + kk) ^ ((r & 7) << 3)];
            r += 16;
            a1 = *(const bf16x8*)&As[(r * 128 + kk) ^ ((r & 7) << 3)];
        }
        #pragma unroll
        for (int cf = 0; cf < NCF; cf++) {
            int c = cf * 16 + fr;
            bf16x8 b = *(const bf16x8*)&Ws[(c * 128 + kk) ^ ((c & 7) << 3)];
            acc[0][cf] = __builtin_amdgcn_mfma_f32_16x16x32_bf16(a0, b, acc[0][cf], 0, 0, 0);
            acc[1][cf] = __builtin_amdgcn_mfma_f32_16x16x32_bf16(a1, b, acc[1][cf], 0, 0, 0);
        }
    }

    const int g4 = (l >> 4) * 4;
    #pragma unroll
    for (int rf = 0; rf < 2; rf++)
        #pragma unroll
        for (int cf = 0; cf < NCF; cf++)
            #pragma unroll
            for (int r = 0; r < 4; r++) {
                int grow = row0 + wv * 32 + rf * 16 + g4 + r;
                if (grow < N_NODES)
                    hb[(size_t)grow * OC + cf * 16 + fr] = f2bf(acc[rf][cf][r]);
            }
}

// ---------------- Aggregation ----------------
// 128ch; output packed bf16 (bit-identical to downstream f2bf staging).
__global__ __launch_bounds__(256) void k_agg128bf(const unsigned int* __restrict__ hb,
                                                  const int* __restrict__ rowptr,
                                                  const int* __restrict__ srcs,
                                                  const float* __restrict__ dinv,
                                                  const float* __restrict__ bias,
                                                  unsigned int* __restrict__ outb,
                                                  int relu) {
    const int l = threadIdx.x & 63;
    const int wv0 = blockIdx.x * 4 + (threadIdx.x >> 6);
    const float2 bv = ((const float2*)bias)[l];

    for (int i = wv0; i < N_NODES; i += AGG_BLOCKS * 4) {
        const float di = dinv[i];
        unsigned int svv = hb[(size_t)i * 64 + l];
        const float sw = di * di;
        float2 acc;
        acc.x = bfbits2f(svv & 0xFFFFu) * sw;
        acc.y = bfbits2f(svv >> 16) * sw;

        const int start = rowptr[i], end = rowptr[i + 1];
        for (int b = start; b < end; b += 64) {
            const int eb = min(end - b, 64);
            int s = 0; float w = 0.f;
            if (l < eb) { s = srcs[b + l]; w = dinv[s] * di; }
            int j = 0;
            for (; j + 8 <= eb; j += 8) {
                int   si[8]; float wi[8];
                #pragma unroll
                for (int u = 0; u < 8; u++) { si[u] = __shfl(s, j + u); wi[u] = __shfl(w, j + u); }
                unsigned int v[8];
                #pragma unroll
                for (int u = 0; u < 8; u++) v[u] = hb[(size_t)si[u] * 64 + l];
                #pragma unroll
                for (int u = 0; u < 8; u++) {
                    acc.x = fmaf(bfbits2f(v[u] & 0xFFFFu), wi[u], acc.x);
                    acc.y = fmaf(bfbits2f(v[u] >> 16),     wi[u], acc.y);
                }
            }
            for (; j < eb; j++) {
                const int   sj = __shfl(s, j);
                const float wj = __shfl(w, j);
                unsigned int v = hb[(size_t)sj * 64 + l];
                acc.x = fmaf(bfbits2f(v & 0xFFFFu), wj, acc.x);
                acc.y = fmaf(bfbits2f(v >> 16),     wj, acc.y);
            }
        }
        acc.x += bv.x; acc.y += bv.y;
        if (relu) { acc.x = fmaxf(acc.x, 0.f); acc.y = fmaxf(acc.y, 0.f); }
        outb[(size_t)i * 64 + l] =
            (unsigned int)f2bf(acc.x) | ((unsigned int)f2bf(acc.y) << 16);
    }
}

__global__ __launch_bounds__(256) void k_agg64bf(const unsigned short* __restrict__ hb,
                                                 const int* __restrict__ rowptr,
                                                 const int* __restrict__ srcs,
                                                 const float* __restrict__ dinv,
                                                 const float* __restrict__ bias,
                                                 float* __restrict__ out,
                                                 int relu) {
    const int l = threadIdx.x & 63;
    const int wv0 = blockIdx.x * 4 + (threadIdx.x >> 6);
    const float bi = bias[l];

    for (int i = wv0; i < N_NODES; i += AGG_BLOCKS * 4) {
        const float di = dinv[i];
        float acc = bfbits2f((unsigned int)hb[(size_t)i * 64 + l]) * (di * di);

        const int start = rowptr[i], end = rowptr[i + 1];
        for (int b = start; b < end; b += 64) {
            const int eb = min(end - b, 64);
            int s = 0; float w = 0.f;
            if (l < eb) { s = srcs[b + l]; w = dinv[s] * di; }
            int j = 0;
            for (; j + 8 <= eb; j += 8) {
                int   si[8]; float wi[8];
                #pragma unroll
                for (int u = 0; u < 8; u++) { si[u] = __shfl(s, j + u); wi[u] = __shfl(w, j + u); }
                unsigned short v[8];
                #pragma unroll
                for (int u = 0; u < 8; u++) v[u] = hb[(size_t)si[u] * 64 + l];
                #pragma unroll
                for (int u = 0; u < 8; u++) acc = fmaf(bfbits2f((unsigned int)v[u]), wi[u], acc);
            }
            for (; j < eb; j++) {
                const int   sj = __shfl(s, j);
                const float wj = __shfl(w, j);
                acc = fmaf(bfbits2f((unsigned int)hb[(size_t)sj * 64 + l]), wj, acc);
            }
        }
        acc += bi;
        if (relu) acc = fmaxf(acc, 0.f);
        out[(size_t)i * 64 + l] = acc;
    }
}

// ---------------- launch ----------------

extern "C" void kernel_launch(void* const* d_in, const int* in_sizes, int n_in,
                              void* d_out, int out_size, void* d_ws, size_t ws_size,
                              hipStream_t stream) {
    const float* x  = (const float*)d_in[0];
    const int*   ei = (const int*)d_in[1];
    const float* W1 = (const float*)d_in[2];
    const float* b1 = (const float*)d_in[3];
    const float* W2 = (const float*)d_in[4];
    const float* b2 = (const float*)d_in[5];
    float* out = (float*)d_out;

    char* p = (char*)d_ws;
    size_t used = 0;
    auto alloc = [&](size_t bytes) {
        void* q = (void*)p;
        size_t pad = (bytes + 255) & ~(size_t)255;
        p += pad;
        used += pad;
        return q;
    };
    int*   rowptr = (int*)alloc(sizeof(int) * (N_NODES + 1));
    float* dinv   = (float*)alloc(sizeof(float) * N_NODES);
    int*   gcur   = (int*)alloc(sizeof(int) * SH64);
    int*   srcs   = (int*)alloc(sizeof(int) * N_EDGES);
    // region A: buckets (13.8MB) then h1b (25.6MB) — buckets dead before gemm1
    void*  regA   = alloc(sizeof(unsigned short) * (size_t)N_NODES * 128);
    long long* buckets = (long long*)regA;
    unsigned short* h1b = (unsigned short*)regA;
    unsigned int* agg1b = (unsigned int*)alloc(sizeof(unsigned int) * (size_t)N_NODES * 64);  // bf16 x 128ch
    unsigned short* h2b = (unsigned short*)alloc(sizeof(unsigned short) * (size_t)N_NODES * 64);

    if (used > ws_size) return;

    hipMemsetAsync(gcur, 0, sizeof(int) * SH64, stream);
    k_bucket64<<<FILL_NCHUNK, 256, 0, stream>>>(ei, gcur, buckets);
    k_build<<<SH64, 1024, 0, stream>>>(buckets, gcur, rowptr, dinv, srcs);

    k_gemm_mfma<128><<<(N_NODES + 127) / 128, 256, 0, stream>>>(x, W1, h1b);
    k_agg128bf<<<AGG_BLOCKS, 256, 0, stream>>>((const unsigned int*)h1b, rowptr, srcs, dinv, b1, agg1b, 1);
    k_gemm_mfma_b<64><<<(N_NODES + 127) / 128, 256, 0, stream>>>((const unsigned short*)agg1b, W2, h2b);
    k_agg64bf<<<AGG_BLOCKS, 256, 0, stream>>>(h2b, rowptr, srcs, dinv, b2, out, 0);
}

// Round 9
// 194.370 us; speedup vs baseline: 1.9278x; 1.1512x over previous
//
#include <hip/hip_runtime.h>
#include <cstdint>
#include <cstddef>

#define N_NODES 100000
#define N_EDGES 1600000
#define IN_CH   128
#define HID_CH  128
#define OUT_CH  64

#define AGG_BLOCKS 2048

#define SH    256
#define SHR   391        // ceil(100000/256); 256*391 = 100096
#define BCAP  7200       // mean 6250, sigma ~79 -> 12 sigma slack
#define BK_CHUNK 4096
#define BK_NBLK ((N_EDGES + BK_CHUNK - 1) / BK_CHUNK)   // 391

__device__ __forceinline__ unsigned short f2bf(float f) {
    unsigned int u = __float_as_uint(f);
    unsigned int r = (u + 0x7FFFu + ((u >> 16) & 1u)) >> 16;   // RNE
    return (unsigned short)r;
}
__device__ __forceinline__ float bfbits2f(unsigned int lo16) {
    return __uint_as_float(lo16 << 16);
}

typedef __attribute__((ext_vector_type(8))) short bf16x8;
typedef __attribute__((ext_vector_type(4))) float f32x4;

// ---------------- CSR build ----------------
// Pass 1: bucket (src,dst) into 256 dst-ranges. 8 wave-private sub-histograms
// (contention ~2/bin); 256 global atomics per block; per-block-per-bin write
// runs average 128B (one line).
__global__ __launch_bounds__(512) void k_bucket(const int* __restrict__ ei,
                                                int* __restrict__ gcur,
                                                long long* __restrict__ buckets) {
    __shared__ int scount[8][SH];
    __shared__ int sbase[8][SH];
    const int tid  = threadIdx.x;
    const int w    = tid >> 6;
    const int base = blockIdx.x * BK_CHUNK;
    for (int i = tid; i < 8 * SH; i += 512) ((int*)scount)[i] = 0;
    __syncthreads();
    int dv[8], sv[8], shd[8], rk[8];
    #pragma unroll
    for (int k = 0; k < 8; k++) {
        int e = base + k * 512 + tid;
        if (e < N_EDGES) {
            dv[k] = __builtin_nontemporal_load(ei + N_EDGES + e);
            sv[k] = __builtin_nontemporal_load(ei + e);
            shd[k] = dv[k] / SHR;
            rk[k] = atomicAdd(&scount[w][shd[k]], 1);   // wave-private LDS bin
        } else shd[k] = -1;
    }
    __syncthreads();
    if (tid < SH) {
        int c[8], tot = 0;
        #pragma unroll
        for (int q = 0; q < 8; q++) { c[q] = scount[q][tid]; tot += c[q]; }
        int run = atomicAdd(&gcur[tid], tot);
        #pragma unroll
        for (int q = 0; q < 8; q++) { sbase[q][tid] = run; run += c[q]; }
    }
    __syncthreads();
    #pragma unroll
    for (int k = 0; k < 8; k++) {
        if (shd[k] >= 0) {
            int pos = sbase[w][shd[k]] + rk[k];
            if (pos < BCAP)
                buckets[(size_t)shd[k] * BCAP + pos] =
                    ((long long)sv[k] << 32) | (unsigned int)dv[k];
        }
    }
}

// Pass 2: one block per range (256 blocks = full CU coverage). In-block
// 256-range prefix (wave 0), histogram -> LDS scan -> rowptr/dinv -> scatter.
// All per-edge atomics LDS-scope.
__global__ __launch_bounds__(1024) void k_build(const long long* __restrict__ buckets,
                                                const int* __restrict__ gcur,
                                                int* __restrict__ rowptr,
                                                float* __restrict__ dinv,
                                                int* __restrict__ srcs) {
    __shared__ int hist[SHR];
    __shared__ int pref[SH];
    __shared__ int wsum[16];
    const int s  = blockIdx.x;
    const int lo = s * SHR;
    const int nb = min(SHR, N_NODES - lo);    // last block: 295
    const int n  = min(gcur[s], BCAP);
    const int t = threadIdx.x, lane = t & 63, wid = t >> 6;
    const long long* bp = buckets + (size_t)s * BCAP;

    if (t < SH) pref[t] = gcur[t];
    for (int i = t; i < SHR; i += 1024) hist[i] = 0;
    __syncthreads();
    if (wid == 0) {   // wave 0: exclusive scan of pref[256], 4 vals/lane
        int v0 = pref[lane * 4], v1 = pref[lane * 4 + 1];
        int v2 = pref[lane * 4 + 2], v3 = pref[lane * 4 + 3];
        int sl = v0 + v1 + v2 + v3;
        int x = sl;
        #pragma unroll
        for (int d = 1; d < 64; d <<= 1) {
            int y = __shfl_up(x, d, 64);
            if (lane >= d) x += y;
        }
        int excl = x - sl;
        pref[lane * 4]     = excl;
        pref[lane * 4 + 1] = excl + v0;
        pref[lane * 4 + 2] = excl + v0 + v1;
        pref[lane * 4 + 3] = excl + v0 + v1 + v2;
        if (s == 0 && lane == 63) rowptr[N_NODES] = x;   // grand total
    }
    __syncthreads();
    const int gbase = pref[s];

    for (int i = t; i < n; i += 1024) {
        atomicAdd(&hist[(int)bp[i] - lo], 1);
    }
    __syncthreads();

    {   // single-chunk block scan of hist[0..391)
        int idx = t;
        int v = (idx < SHR) ? hist[idx] : 0;
        int x = v;
        #pragma unroll
        for (int d = 1; d < 64; d <<= 1) {
            int y = __shfl_up(x, d, 64);
            if (lane >= d) x += y;
        }
        if (lane == 63) wsum[wid] = x;
        __syncthreads();
        if (wid == 0) {
            int sv = (lane < 16) ? wsum[lane] : 0;
            #pragma unroll
            for (int d = 1; d < 16; d <<= 1) {
                int y = __shfl_up(sv, d, 64);
                if (lane >= d) sv += y;
            }
            if (lane < 16) wsum[lane] = sv;
        }
        __syncthreads();
        int woff = (wid == 0) ? 0 : wsum[wid - 1];
        int excl = woff + (x - v);
        if (idx < nb) {
            rowptr[lo + idx] = gbase + excl;
            dinv[lo + idx]   = rsqrtf((float)(v + 1));   // +1 self-loop
        }
        if (idx < SHR) hist[idx] = excl;                  // becomes cursor
        __syncthreads();
    }

    for (int i = t; i < n; i += 1024) {
        long long v = bp[i];
        int d  = (int)v;
        int sv = (int)(v >> 32);
        int pos = atomicAdd(&hist[d - lo], 1);
        srcs[gbase + pos] = sv;
    }
}

// ---------------- GEMM: bf16 MFMA (16x16x32), K=128 single residency ----------------
template <int OC>
__global__ __launch_bounds__(256) void k_gemm_mfma(const float* __restrict__ A,
                                                   const float* __restrict__ W,
                                                   unsigned short* __restrict__ hb) {
    __shared__ unsigned short As[128 * 128];
    __shared__ unsigned short Ws[OC * 128];
    const int tid = threadIdx.x;
    const int l   = tid & 63;
    const int wv  = tid >> 6;
    const int row0 = blockIdx.x * 128;

    #pragma unroll
    for (int it = 0; it < 16; it++) {
        int idx4 = it * 256 + tid;
        int r = idx4 >> 5, c4 = idx4 & 31;
        int gr = row0 + r; if (gr >= N_NODES) gr = N_NODES - 1;
        float4 v = ((const float4*)(A + (size_t)gr * 128))[c4];
        int bi = (r * 128 + c4 * 4) ^ ((r & 7) << 3);
        ushort4 pk;
        pk.x = f2bf(v.x); pk.y = f2bf(v.y); pk.z = f2bf(v.z); pk.w = f2bf(v.w);
        *(ushort4*)&As[bi] = pk;
    }
    for (int idx = tid; idx < 128 * OC; idx += 256) {
        int k = idx / OC, c = idx % OC;
        Ws[(c * 128 + k) ^ ((c & 7) << 3)] = f2bf(W[idx]);
    }
    __syncthreads();

    constexpr int NCF = OC / 16;
    f32x4 acc[2][NCF];
    #pragma unroll
    for (int a = 0; a < 2; a++)
        #pragma unroll
        for (int b = 0; b < NCF; b++) acc[a][b] = {0.f, 0.f, 0.f, 0.f};

    const int fr = l & 15;
    const int kg = (l >> 4) * 8;

    #pragma unroll
    for (int ks = 0; ks < 4; ks++) {
        const int kk = ks * 32 + kg;
        bf16x8 a0, a1;
        {
            int r = wv * 32 + fr;
            a0 = *(const bf16x8*)&As[(r * 128 + kk) ^ ((r & 7) << 3)];
            r += 16;
            a1 = *(const bf16x8*)&As[(r * 128 + kk) ^ ((r & 7) << 3)];
        }
        #pragma unroll
        for (int cf = 0; cf < NCF; cf++) {
            int c = cf * 16 + fr;
            bf16x8 b = *(const bf16x8*)&Ws[(c * 128 + kk) ^ ((c & 7) << 3)];
            acc[0][cf] = __builtin_amdgcn_mfma_f32_16x16x32_bf16(a0, b, acc[0][cf], 0, 0, 0);
            acc[1][cf] = __builtin_amdgcn_mfma_f32_16x16x32_bf16(a1, b, acc[1][cf], 0, 0, 0);
        }
    }

    const int g4 = (l >> 4) * 4;
    #pragma unroll
    for (int rf = 0; rf < 2; rf++)
        #pragma unroll
        for (int cf = 0; cf < NCF; cf++)
            #pragma unroll
            for (int r = 0; r < 4; r++) {
                int grow = row0 + wv * 32 + rf * 16 + g4 + r;
                if (grow < N_NODES)
                    hb[(size_t)grow * OC + cf * 16 + fr] = f2bf(acc[rf][cf][r]);
            }
}

template <int OC>
__global__ __launch_bounds__(256) void k_gemm_mfma_b(const unsigned short* __restrict__ A,
                                                     const float* __restrict__ W,
                                                     unsigned short* __restrict__ hb) {
    __shared__ unsigned short As[128 * 128];
    __shared__ unsigned short Ws[OC * 128];
    const int tid = threadIdx.x;
    const int l   = tid & 63;
    const int wv  = tid >> 6;
    const int row0 = blockIdx.x * 128;

    #pragma unroll
    for (int it = 0; it < 8; it++) {
        int idx8 = it * 256 + tid;
        int r = idx8 >> 4, c8 = idx8 & 15;
        int gr = row0 + r; if (gr >= N_NODES) gr = N_NODES - 1;
        uint4 v = ((const uint4*)(A + (size_t)gr * 128))[c8];
        int bi = (r * 128 + c8 * 8) ^ ((r & 7) << 3);
        *(uint4*)&As[bi] = v;
    }
    for (int idx = tid; idx < 128 * OC; idx += 256) {
        int k = idx / OC, c = idx % OC;
        Ws[(c * 128 + k) ^ ((c & 7) << 3)] = f2bf(W[idx]);
    }
    __syncthreads();

    constexpr int NCF = OC / 16;
    f32x4 acc[2][NCF];
    #pragma unroll
    for (int a = 0; a < 2; a++)
        #pragma unroll
        for (int b = 0; b < NCF; b++) acc[a][b] = {0.f, 0.f, 0.f, 0.f};

    const int fr = l & 15;
    const int kg = (l >> 4) * 8;

    #pragma unroll
    for (int ks = 0; ks < 4; ks++) {
        const int kk = ks * 32 + kg;
        bf16x8 a0, a1;
        {
            int r = wv * 32 + fr;
            a0 = *(const bf16x8*)&As[(r * 128 + kk) ^ ((r & 7) << 3)];
            r += 16;
            a1 = *(const bf16x8*)&As[(r * 128 + kk) ^ ((r & 7) << 3)];
        }
        #pragma unroll
        for (int cf = 0; cf < NCF; cf++) {
            int c = cf * 16 + fr;
            bf16x8 b = *(const bf16x8*)&Ws[(c * 128 + kk) ^ ((c & 7) << 3)];
            acc[0][cf] = __builtin_amdgcn_mfma_f32_16x16x32_bf16(a0, b, acc[0][cf], 0, 0, 0);
            acc[1][cf] = __builtin_amdgcn_mfma_f32_16x16x32_bf16(a1, b, acc[1][cf], 0, 0, 0);
        }
    }

    const int g4 = (l >> 4) * 4;
    #pragma unroll
    for (int rf = 0; rf < 2; rf++)
        #pragma unroll
        for (int cf = 0; cf < NCF; cf++)
            #pragma unroll
            for (int r = 0; r < 4; r++) {
                int grow = row0 + wv * 32 + rf * 16 + g4 + r;
                if (grow < N_NODES)
                    hb[(size_t)grow * OC + cf * 16 + fr] = f2bf(acc[rf][cf][r]);
            }
}

// ---------------- Aggregation ----------------
__global__ __launch_bounds__(256) void k_agg128bf(const unsigned int* __restrict__ hb,
                                                  const int* __restrict__ rowptr,
                                                  const int* __restrict__ srcs,
                                                  const float* __restrict__ dinv,
                                                  const float* __restrict__ bias,
                                                  unsigned int* __restrict__ outb,
                                                  int relu) {
    const int l = threadIdx.x & 63;
    const int wv0 = blockIdx.x * 4 + (threadIdx.x >> 6);
    const float2 bv = ((const float2*)bias)[l];

    for (int i = wv0; i < N_NODES; i += AGG_BLOCKS * 4) {
        const float di = dinv[i];
        unsigned int svv = hb[(size_t)i * 64 + l];
        const float sw = di * di;
        float2 acc;
        acc.x = bfbits2f(svv & 0xFFFFu) * sw;
        acc.y = bfbits2f(svv >> 16) * sw;

        const int start = rowptr[i], end = rowptr[i + 1];
        for (int b = start; b < end; b += 64) {
            const int eb = min(end - b, 64);
            int s = 0; float w = 0.f;
            if (l < eb) { s = srcs[b + l]; w = dinv[s] * di; }
            int j = 0;
            for (; j + 8 <= eb; j += 8) {
                int   si[8]; float wi[8];
                #pragma unroll
                for (int u = 0; u < 8; u++) { si[u] = __shfl(s, j + u); wi[u] = __shfl(w, j + u); }
                unsigned int v[8];
                #pragma unroll
                for (int u = 0; u < 8; u++) v[u] = hb[(size_t)si[u] * 64 + l];
                #pragma unroll
                for (int u = 0; u < 8; u++) {
                    acc.x = fmaf(bfbits2f(v[u] & 0xFFFFu), wi[u], acc.x);
                    acc.y = fmaf(bfbits2f(v[u] >> 16),     wi[u], acc.y);
                }
            }
            for (; j + 4 <= eb; j += 4) {
                int   si[4]; float wi[4];
                #pragma unroll
                for (int u = 0; u < 4; u++) { si[u] = __shfl(s, j + u); wi[u] = __shfl(w, j + u); }
                unsigned int v[4];
                #pragma unroll
                for (int u = 0; u < 4; u++) v[u] = hb[(size_t)si[u] * 64 + l];
                #pragma unroll
                for (int u = 0; u < 4; u++) {
                    acc.x = fmaf(bfbits2f(v[u] & 0xFFFFu), wi[u], acc.x);
                    acc.y = fmaf(bfbits2f(v[u] >> 16),     wi[u], acc.y);
                }
            }
            for (; j < eb; j++) {
                const int   sj = __shfl(s, j);
                const float wj = __shfl(w, j);
                unsigned int v = hb[(size_t)sj * 64 + l];
                acc.x = fmaf(bfbits2f(v & 0xFFFFu), wj, acc.x);
                acc.y = fmaf(bfbits2f(v >> 16),     wj, acc.y);
            }
        }
        acc.x += bv.x; acc.y += bv.y;
        if (relu) { acc.x = fmaxf(acc.x, 0.f); acc.y = fmaxf(acc.y, 0.f); }
        outb[(size_t)i * 64 + l] =
            (unsigned int)f2bf(acc.x) | ((unsigned int)f2bf(acc.y) << 16);
    }
}

__global__ __launch_bounds__(256) void k_agg64bf(const unsigned short* __restrict__ hb,
                                                 const int* __restrict__ rowptr,
                                                 const int* __restrict__ srcs,
                                                 const float* __restrict__ dinv,
                                                 const float* __restrict__ bias,
                                                 float* __restrict__ out,
                                                 int relu) {
    const int l = threadIdx.x & 63;
    const int wv0 = blockIdx.x * 4 + (threadIdx.x >> 6);
    const float bi = bias[l];

    for (int i = wv0; i < N_NODES; i += AGG_BLOCKS * 4) {
        const float di = dinv[i];
        float acc = bfbits2f((unsigned int)hb[(size_t)i * 64 + l]) * (di * di);

        const int start = rowptr[i], end = rowptr[i + 1];
        for (int b = start; b < end; b += 64) {
            const int eb = min(end - b, 64);
            int s = 0; float w = 0.f;
            if (l < eb) { s = srcs[b + l]; w = dinv[s] * di; }
            int j = 0;
            for (; j + 8 <= eb; j += 8) {
                int   si[8]; float wi[8];
                #pragma unroll
                for (int u = 0; u < 8; u++) { si[u] = __shfl(s, j + u); wi[u] = __shfl(w, j + u); }
                unsigned short v[8];
                #pragma unroll
                for (int u = 0; u < 8; u++) v[u] = hb[(size_t)si[u] * 64 + l];
                #pragma unroll
                for (int u = 0; u < 8; u++) acc = fmaf(bfbits2f((unsigned int)v[u]), wi[u], acc);
            }
            for (; j + 4 <= eb; j += 4) {
                int   si[4]; float wi[4];
                #pragma unroll
                for (int u = 0; u < 4; u++) { si[u] = __shfl(s, j + u); wi[u] = __shfl(w, j + u); }
                unsigned short v[4];
                #pragma unroll
                for (int u = 0; u < 4; u++) v[u] = hb[(size_t)si[u] * 64 + l];
                #pragma unroll
                for (int u = 0; u < 4; u++) acc = fmaf(bfbits2f((unsigned int)v[u]), wi[u], acc);
            }
            for (; j < eb; j++) {
                const int   sj = __shfl(s, j);
                const float wj = __shfl(w, j);
                acc = fmaf(bfbits2f((unsigned int)hb[(size_t)sj * 64 + l]), wj, acc);
            }
        }
        acc += bi;
        if (relu) acc = fmaxf(acc, 0.f);
        out[(size_t)i * 64 + l] = acc;
    }
}

// ---------------- launch ----------------

extern "C" void kernel_launch(void* const* d_in, const int* in_sizes, int n_in,
                              void* d_out, int out_size, void* d_ws, size_t ws_size,
                              hipStream_t stream) {
    const float* x  = (const float*)d_in[0];
    const int*   ei = (const int*)d_in[1];
    const float* W1 = (const float*)d_in[2];
    const float* b1 = (const float*)d_in[3];
    const float* W2 = (const float*)d_in[4];
    const float* b2 = (const float*)d_in[5];
    float* out = (float*)d_out;

    char* p = (char*)d_ws;
    size_t used = 0;
    auto alloc = [&](size_t bytes) {
        void* q = (void*)p;
        size_t pad = (bytes + 255) & ~(size_t)255;
        p += pad;
        used += pad;
        return q;
    };
    int*   rowptr = (int*)alloc(sizeof(int) * (N_NODES + 1));
    float* dinv   = (float*)alloc(sizeof(float) * N_NODES);
    int*   gcur   = (int*)alloc(sizeof(int) * SH);
    int*   srcs   = (int*)alloc(sizeof(int) * N_EDGES);
    // region A: buckets (256*7200*8B = 14.75MB) then h1b (25.6MB)
    void*  regA   = alloc(sizeof(unsigned short) * (size_t)N_NODES * 128);
    long long* buckets = (long long*)regA;
    unsigned short* h1b = (unsigned short*)regA;
    unsigned int* agg1b = (unsigned int*)alloc(sizeof(unsigned int) * (size_t)N_NODES * 64);
    unsigned short* h2b = (unsigned short*)alloc(sizeof(unsigned short) * (size_t)N_NODES * 64);

    if (used > ws_size) return;

    hipMemsetAsync(gcur, 0, sizeof(int) * SH, stream);
    k_bucket<<<BK_NBLK, 512, 0, stream>>>(ei, gcur, buckets);
    k_build<<<SH, 1024, 0, stream>>>(buckets, gcur, rowptr, dinv, srcs);

    k_gemm_mfma<128><<<(N_NODES + 127) / 128, 256, 0, stream>>>(x, W1, h1b);
    k_agg128bf<<<AGG_BLOCKS, 256, 0, stream>>>((const unsigned int*)h1b, rowptr, srcs, dinv, b1, agg1b, 1);
    k_gemm_mfma_b<64><<<(N_NODES + 127) / 128, 256, 0, stream>>>((const unsigned short*)agg1b, W2, h2b);
    k_agg64bf<<<AGG_BLOCKS, 256, 0, stream>>>(h2b, rowptr, srcs, dinv, b2, out, 0);
}